// Round 1
// baseline (205.791 us; speedup 1.0000x reference)
//
#include <hip/hip_runtime.h>
#include <hip/hip_bf16.h>
#include <stdint.h>

// Problem constants
#define NB   4096      // rows per input matrix
#define DTOT 256       // feature dim
#define NTOT 8192      // 2*NB

// Workspace byte layout:
//   0     double S            (sum of row sq-norms)
//   8     double Sxx
//   16    double Syy
//   24    double Sxy2         (XY + YX quadrants combined)
//   32    double wfac         (Sw^2 / (Sw^2 + 1e-8))
//   40    float  scale        (log2(e)/bandwidth)
//   48    double m[256]       (column sums)
//   2112  float  sq[8192]
//   34944 ushort tot[8192*256]  (bf16 total matrix)
#define WS_SQ_OFF   2112
#define WS_TOT_OFF  34944

typedef __attribute__((ext_vector_type(8))) short bf16x8;
typedef __attribute__((ext_vector_type(4))) float f32x4;

__device__ __forceinline__ unsigned short f2bf(float f) {
    unsigned int u = __float_as_uint(f);
    unsigned int r = (u + 0x7FFFu + ((u >> 16) & 1u)) >> 16;   // RNE
    return (unsigned short)r;
}

// ---------------- kernel 0: zero the accumulator header ----------------
__global__ void k_zero(double* wsd) {
    int t = threadIdx.x;
    for (int i = t; i < 264; i += 256) wsd[i] = 0.0;
}

// ---------------- kernel A: row sq-norms + bf16 convert ----------------
__global__ __launch_bounds__(256) void k_rows(const float* __restrict__ src,
                                              const float* __restrict__ tgt,
                                              float* __restrict__ sq,
                                              unsigned short* __restrict__ tot,
                                              double* __restrict__ Sacc) {
    int lane = threadIdx.x & 63;
    int rsub = threadIdx.x >> 6;
    int r = blockIdx.x * 4 + rsub;
    const float* p = (r < NB) ? (src + (size_t)r * DTOT)
                              : (tgt + (size_t)(r - NB) * DTOT);
    float4 v = *(const float4*)(p + lane * 4);
    float s = v.x * v.x + v.y * v.y + v.z * v.z + v.w * v.w;
    ushort4 u;
    u.x = f2bf(v.x); u.y = f2bf(v.y); u.z = f2bf(v.z); u.w = f2bf(v.w);
    *(ushort4*)(tot + (size_t)r * DTOT + lane * 4) = u;
    for (int off = 32; off; off >>= 1) s += __shfl_down(s, off, 64);
    if (lane == 0) {
        sq[r] = s;
        atomicAdd(Sacc, (double)s);
    }
}

// ---------------- kernel A2: column sums (for ||sum x||^2) ----------------
__global__ __launch_bounds__(256) void k_colsum(const float* __restrict__ src,
                                                const float* __restrict__ tgt,
                                                double* __restrict__ m) {
    int c = threadIdx.x;
    int r0 = blockIdx.x * 256;
    double s = 0.0;
    for (int k = 0; k < 256; ++k) {
        int r = r0 + k;
        const float* p = (r < NB) ? (src + (size_t)r * DTOT)
                                  : (tgt + (size_t)(r - NB) * DTOT);
        s += (double)p[c];
    }
    atomicAdd(&m[c], s);
}

// ---------------- kernel B: bandwidth + weighting constants ----------------
__global__ __launch_bounds__(256) void k_consts(const float* __restrict__ s1,
                                                const float* __restrict__ s2,
                                                double* __restrict__ wsd,
                                                float* __restrict__ scale_out) {
    __shared__ double red[256];
    int t = threadIdx.x;
    // Sw = sum sigmoid(|s1-s2|)
    double sw = 0.0;
    for (int i = t; i < NB; i += 256) {
        double d = fabs((double)s1[i] - (double)s2[i]);
        sw += 1.0 / (1.0 + exp(-d));
    }
    red[t] = sw; __syncthreads();
    for (int off = 128; off; off >>= 1) { if (t < off) red[t] += red[t + off]; __syncthreads(); }
    double Sw = red[0]; __syncthreads();
    // ||m||^2
    double mv = wsd[6 + t];
    red[t] = mv * mv; __syncthreads();
    for (int off = 128; off; off >>= 1) { if (t < off) red[t] += red[t + off]; __syncthreads(); }
    if (t == 0) {
        double M2 = red[0];
        double S = wsd[0];
        double sumL2 = 2.0 * (double)NTOT * S - 2.0 * M2;   // clamp effect negligible (diag ~ 0)
        double nn = (double)NTOT * (double)NTOT - (double)NTOT;
        double bw = sumL2 / nn;
        bw = bw * 0.25;                                      // / KERNEL_MUL^(KERNEL_NUM//2) = /4
        double SW = Sw * Sw;
        wsd[4] = SW / (SW + 1e-8);                           // wfac
        *scale_out = (float)(1.4426950408889634 / bw);       // log2(e)/bw
    }
}

// ---------------- kernel C: fused GEMM + RBF epilogue + quadrant reduce ----------------
__global__ __launch_bounds__(256) void k_mmd(const unsigned short* __restrict__ tot,
                                             const float* __restrict__ sq,
                                             const float* __restrict__ scale_p,
                                             double* __restrict__ acc_out) {
    __shared__ unsigned short lds_a[128 * 64];
    __shared__ unsigned short lds_b[128 * 64];
    __shared__ double blkred[4];

    const int tid  = threadIdx.x;
    const int lane = tid & 63;
    const int wid  = tid >> 6;
    const int brow = blockIdx.y * 128;
    const int bcol = blockIdx.x * 128;
    const int wm = wid >> 1, wn = wid & 1;

    const unsigned short* gA = tot + (size_t)brow * DTOT;
    const unsigned short* gB = tot + (size_t)bcol * DTOT;

    f32x4 acc[4][4] = {};

    const int rA   = wid * 32 + (lane >> 3);     // staging row within tile (+ q*8)
    const int cLan = (lane & 7) * 8;             // staging col element offset within K-step

    for (int ki = 0; ki < 4; ++ki) {
        const int cOff = ki * 64 + cLan;
#pragma unroll
        for (int q = 0; q < 4; ++q) {
            const unsigned short* ga = gA + (size_t)(rA + q * 8) * DTOT + cOff;
            __builtin_amdgcn_global_load_lds(
                (const __attribute__((address_space(1))) void*)ga,
                (__attribute__((address_space(3))) void*)(lds_a + (wid * 32 + q * 8) * 64),
                16, 0, 0);
        }
#pragma unroll
        for (int q = 0; q < 4; ++q) {
            const unsigned short* gb = gB + (size_t)(rA + q * 8) * DTOT + cOff;
            __builtin_amdgcn_global_load_lds(
                (const __attribute__((address_space(1))) void*)gb,
                (__attribute__((address_space(3))) void*)(lds_b + (wid * 32 + q * 8) * 64),
                16, 0, 0);
        }
        __syncthreads();
#pragma unroll
        for (int kk = 0; kk < 2; ++kk) {
            bf16x8 af[4], bfr[4];
            const int krd = kk * 32 + (lane >> 4) * 8;
#pragma unroll
            for (int mi = 0; mi < 4; ++mi)
                af[mi] = *(const bf16x8*)(lds_a + (wm * 64 + mi * 16 + (lane & 15)) * 64 + krd);
#pragma unroll
            for (int ni = 0; ni < 4; ++ni)
                bfr[ni] = *(const bf16x8*)(lds_b + (wn * 64 + ni * 16 + (lane & 15)) * 64 + krd);
#pragma unroll
            for (int mi = 0; mi < 4; ++mi)
#pragma unroll
                for (int ni = 0; ni < 4; ++ni)
                    acc[mi][ni] = __builtin_amdgcn_mfma_f32_16x16x32_bf16(
                        af[mi], bfr[ni], acc[mi][ni], 0, 0, 0);
        }
        __syncthreads();
    }

    // ---- fused epilogue: L2 -> 5-bandwidth RBF sum -> quadrant accumulate ----
    const float scale = *scale_p;   // log2(e)/bw
    float part = 0.0f;
    float sqj[4];
#pragma unroll
    for (int ni = 0; ni < 4; ++ni)
        sqj[ni] = sq[bcol + wn * 64 + ni * 16 + (lane & 15)];
#pragma unroll
    for (int mi = 0; mi < 4; ++mi) {
        float sqi[4];
#pragma unroll
        for (int r = 0; r < 4; ++r)
            sqi[r] = sq[brow + wm * 64 + mi * 16 + (lane >> 4) * 4 + r];
#pragma unroll
        for (int ni = 0; ni < 4; ++ni) {
#pragma unroll
            for (int r = 0; r < 4; ++r) {
                float l2 = sqi[r] + sqj[ni] - 2.0f * acc[mi][ni][r];
                l2 = fmaxf(l2, 0.0f);
                float a = l2 * scale;
                float k4 = exp2f(-a * 0.0625f);   // exp(-L2/(bw*16))
                float k3 = k4 * k4;
                float k2 = k3 * k3;
                float k1 = k2 * k2;
                float k0 = k1 * k1;
                part += ((k4 + k3) + (k2 + k1)) + k0;
            }
        }
    }
    for (int off = 32; off; off >>= 1) part += __shfl_down(part, off, 64);
    if (lane == 0) blkred[wid] = (double)part;
    __syncthreads();
    if (tid == 0) {
        double tsum = blkred[0] + blkred[1] + blkred[2] + blkred[3];
        int qi = (brow < NB) ? ((bcol < NB) ? 0 : 2) : ((bcol < NB) ? 2 : 1);
        atomicAdd(&acc_out[qi], tsum);
    }
}

// ---------------- kernel D: finalize ----------------
__global__ void k_final(const double* __restrict__ wsd, float* __restrict__ out) {
    double inv = 1.0 / ((double)NB * (double)NB);
    double XX  = wsd[1] * inv;
    double YY  = wsd[2] * inv;
    double XY2 = wsd[3] * inv;   // XY + YX
    out[0] = (float)(wsd[4] * XX + YY - XY2);
}

extern "C" void kernel_launch(void* const* d_in, const int* in_sizes, int n_in,
                              void* d_out, int out_size, void* d_ws, size_t ws_size,
                              hipStream_t stream) {
    const float* src = (const float*)d_in[0];
    const float* tgt = (const float*)d_in[1];
    const float* s1  = (const float*)d_in[2];
    const float* s2  = (const float*)d_in[3];
    float* out = (float*)d_out;

    char* ws = (char*)d_ws;
    double* wsd = (double*)ws;
    float* scale_p = (float*)(ws + 40);
    double* m = wsd + 6;
    float* sq = (float*)(ws + WS_SQ_OFF);
    unsigned short* tot = (unsigned short*)(ws + WS_TOT_OFF);

    hipLaunchKernelGGL(k_zero,   dim3(1),      dim3(256), 0, stream, wsd);
    hipLaunchKernelGGL(k_rows,   dim3(NTOT/4), dim3(256), 0, stream, src, tgt, sq, tot, wsd);
    hipLaunchKernelGGL(k_colsum, dim3(32),     dim3(256), 0, stream, src, tgt, m);
    hipLaunchKernelGGL(k_consts, dim3(1),      dim3(256), 0, stream, s1, s2, wsd, scale_p);
    hipLaunchKernelGGL(k_mmd,    dim3(64, 64), dim3(256), 0, stream, tot, sq, scale_p, wsd + 1);
    hipLaunchKernelGGL(k_final,  dim3(1),      dim3(1),   0, stream, wsd, out);
}

// Round 3
// 80.023 us; speedup vs baseline: 2.5717x; 2.5717x over previous
//
#include <hip/hip_runtime.h>
#include <hip/hip_bf16.h>
#include <stdint.h>

// Problem constants
#define NB   4096      // rows per input matrix
#define DTOT 256       // feature dim
#define NTOT 8192      // 2*NB
#define NBLK 64        // 8192 / 128 tile blocks per side

// Workspace layout (doubles unless noted):
//   wsd[0]              wfac = Sw^2/(Sw^2+1e-8)
//   bytes 8..12         float scale = log2(e)/bandwidth
//   wsd[2..258)         m[256] column sums
//   wsd[258..354)       acc slots: [q*32 + s], q=0:XX 1:YY 2:XY+YX
//   bytes 3072..35840   float sq[8192]
//   bytes 35840..       ushort tot[8192*256] bf16
#define WSD_M      2
#define WSD_ACC    258
#define WSD_ZEND   354
#define WS_SQ_OFF  3072
#define WS_TOT_OFF 35840

typedef __attribute__((ext_vector_type(8))) short bf16x8;
typedef __attribute__((ext_vector_type(4))) float f32x4;

__device__ __forceinline__ unsigned short f2bf(float f) {
    unsigned int u = __float_as_uint(f);
    unsigned int r = (u + 0x7FFFu + ((u >> 16) & 1u)) >> 16;   // RNE
    return (unsigned short)r;
}

// ---------------- kernel 0: zero the accumulator header ----------------
__global__ void k_zero(double* wsd) {
    int t = threadIdx.x;
    for (int i = t; i < WSD_ZEND; i += 256) wsd[i] = 0.0;
}

// ---------------- kernel A: row sq-norms + bf16 convert (no atomics) ----------------
__global__ __launch_bounds__(256) void k_rows(const float* __restrict__ src,
                                              const float* __restrict__ tgt,
                                              float* __restrict__ sq,
                                              unsigned short* __restrict__ tot) {
    int lane = threadIdx.x & 63;
    int rsub = threadIdx.x >> 6;
    int r = blockIdx.x * 4 + rsub;
    const float* p = (r < NB) ? (src + (size_t)r * DTOT)
                              : (tgt + (size_t)(r - NB) * DTOT);
    float4 v = *(const float4*)(p + lane * 4);
    float s = v.x * v.x + v.y * v.y + v.z * v.z + v.w * v.w;
    ushort4 u;
    u.x = f2bf(v.x); u.y = f2bf(v.y); u.z = f2bf(v.z); u.w = f2bf(v.w);
    *(ushort4*)(tot + (size_t)r * DTOT + lane * 4) = u;
    for (int off = 32; off; off >>= 1) s += __shfl_down(s, off, 64);
    if (lane == 0) sq[r] = s;
}

// ---------------- kernel A2: column sums (for ||sum x||^2) ----------------
__global__ __launch_bounds__(256) void k_colsum(const float* __restrict__ src,
                                                const float* __restrict__ tgt,
                                                double* __restrict__ m) {
    int c = threadIdx.x;
    int r0 = blockIdx.x * 32;
    double s = 0.0;
    for (int k = 0; k < 32; ++k) {
        int r = r0 + k;
        const float* p = (r < NB) ? (src + (size_t)r * DTOT)
                                  : (tgt + (size_t)(r - NB) * DTOT);
        s += (double)p[c];
    }
    atomicAdd(&m[c], s);
}

// ---------------- kernel B: bandwidth + weighting constants ----------------
__global__ __launch_bounds__(256) void k_consts(const float* __restrict__ s1,
                                                const float* __restrict__ s2,
                                                const float* __restrict__ sq,
                                                double* __restrict__ wsd,
                                                float* __restrict__ scale_out) {
    __shared__ double red[256];
    int t = threadIdx.x;
    // Sw = sum sigmoid(|s1-s2|)
    double sw = 0.0;
    for (int i = t; i < NB; i += 256) {
        double d = fabs((double)s1[i] - (double)s2[i]);
        sw += 1.0 / (1.0 + exp(-d));
    }
    red[t] = sw; __syncthreads();
    for (int off = 128; off; off >>= 1) { if (t < off) red[t] += red[t + off]; __syncthreads(); }
    double Sw = red[0]; __syncthreads();
    // S = sum of row sq-norms
    double ss = 0.0;
    for (int i = t; i < NTOT; i += 256) ss += (double)sq[i];
    red[t] = ss; __syncthreads();
    for (int off = 128; off; off >>= 1) { if (t < off) red[t] += red[t + off]; __syncthreads(); }
    double S = red[0]; __syncthreads();
    // ||m||^2
    double mv = wsd[WSD_M + t];
    red[t] = mv * mv; __syncthreads();
    for (int off = 128; off; off >>= 1) { if (t < off) red[t] += red[t + off]; __syncthreads(); }
    if (t == 0) {
        double M2 = red[0];
        double sumL2 = 2.0 * (double)NTOT * S - 2.0 * M2;   // clamp effect negligible (diag ~ 0)
        double nn = (double)NTOT * (double)NTOT - (double)NTOT;
        double bw = (sumL2 / nn) * 0.25;                    // / KERNEL_MUL^(KERNEL_NUM//2)
        double SW = Sw * Sw;
        wsd[0] = SW / (SW + 1e-8);                          // wfac
        *scale_out = (float)(1.4426950408889634 / bw);      // log2(e)/bw
    }
}

// ---------------- kernel C: fused GEMM + RBF epilogue, upper-triangular blocks ----------------
__global__ __launch_bounds__(256) void k_mmd(const unsigned short* __restrict__ tot,
                                             const float* __restrict__ sq,
                                             const float* __restrict__ scale_p,
                                             double* __restrict__ acc_out) {
    __shared__ unsigned short lds_a[128 * 64];
    __shared__ unsigned short lds_b[128 * 64];
    __shared__ double blkred[4];

    // decode upper-triangular block index: t -> (bi, bj), bi <= bj
    const int t = blockIdx.x;
    int bi = (int)((2.0f * NBLK + 1.0f
                    - sqrtf((2.0f * NBLK + 1.0f) * (2.0f * NBLK + 1.0f) - 8.0f * (float)t)) * 0.5f);
    while (bi > 0 && bi * (2 * NBLK - bi + 1) / 2 > t) --bi;
    while ((bi + 1) * (2 * NBLK - bi) / 2 <= t) ++bi;
    const int bj = bi + (t - bi * (2 * NBLK - bi + 1) / 2);

    const int tid  = threadIdx.x;
    const int lane = tid & 63;
    const int wid  = tid >> 6;
    const int brow = bi * 128;
    const int bcol = bj * 128;
    const int wm = wid >> 1, wn = wid & 1;

    const unsigned short* gA = tot + (size_t)brow * DTOT;
    const unsigned short* gB = tot + (size_t)bcol * DTOT;

    f32x4 acc[4][4] = {};

    const int rA   = wid * 32 + (lane >> 3);     // staging row within tile (+ q*8)
    const int cLan = (lane & 7) * 8;             // staging col element offset within K-step

    for (int ki = 0; ki < 4; ++ki) {
        const int cOff = ki * 64 + cLan;
#pragma unroll
        for (int q = 0; q < 4; ++q) {
            const unsigned short* ga = gA + (size_t)(rA + q * 8) * DTOT + cOff;
            __builtin_amdgcn_global_load_lds(
                (const __attribute__((address_space(1))) void*)ga,
                (__attribute__((address_space(3))) void*)(lds_a + (wid * 32 + q * 8) * 64),
                16, 0, 0);
        }
#pragma unroll
        for (int q = 0; q < 4; ++q) {
            const unsigned short* gb = gB + (size_t)(rA + q * 8) * DTOT + cOff;
            __builtin_amdgcn_global_load_lds(
                (const __attribute__((address_space(1))) void*)gb,
                (__attribute__((address_space(3))) void*)(lds_b + (wid * 32 + q * 8) * 64),
                16, 0, 0);
        }
        __syncthreads();
#pragma unroll
        for (int kk = 0; kk < 2; ++kk) {
            bf16x8 af[4], bfr[4];
            const int krd = kk * 32 + (lane >> 4) * 8;
#pragma unroll
            for (int mi = 0; mi < 4; ++mi)
                af[mi] = *(const bf16x8*)(lds_a + (wm * 64 + mi * 16 + (lane & 15)) * 64 + krd);
#pragma unroll
            for (int ni = 0; ni < 4; ++ni)
                bfr[ni] = *(const bf16x8*)(lds_b + (wn * 64 + ni * 16 + (lane & 15)) * 64 + krd);
#pragma unroll
            for (int mi = 0; mi < 4; ++mi)
#pragma unroll
                for (int ni = 0; ni < 4; ++ni)
                    acc[mi][ni] = __builtin_amdgcn_mfma_f32_16x16x32_bf16(
                        af[mi], bfr[ni], acc[mi][ni], 0, 0, 0);
        }
        __syncthreads();
    }

    // ---- fused epilogue: L2 -> 5-bandwidth RBF sum -> quadrant accumulate ----
    const float scale = *scale_p;   // log2(e)/bw
    float part = 0.0f;
    float sqj[4];
#pragma unroll
    for (int ni = 0; ni < 4; ++ni)
        sqj[ni] = sq[bcol + wn * 64 + ni * 16 + (lane & 15)];
#pragma unroll
    for (int mi = 0; mi < 4; ++mi) {
        float sqi[4];
#pragma unroll
        for (int r = 0; r < 4; ++r)
            sqi[r] = sq[brow + wm * 64 + mi * 16 + (lane >> 4) * 4 + r];
#pragma unroll
        for (int ni = 0; ni < 4; ++ni) {
#pragma unroll
            for (int r = 0; r < 4; ++r) {
                float l2 = sqi[r] + sqj[ni] - 2.0f * acc[mi][ni][r];
                l2 = fmaxf(l2, 0.0f);
                float a = l2 * scale;
                float k4 = exp2f(-a * 0.0625f);   // exp(-L2/(bw*16))
                float k3 = k4 * k4;
                float k2 = k3 * k3;
                float k1 = k2 * k2;
                float k0 = k1 * k1;
                part += ((k4 + k3) + (k2 + k1)) + k0;
            }
        }
    }
    for (int off = 32; off; off >>= 1) part += __shfl_down(part, off, 64);
    if (lane == 0) blkred[wid] = (double)part;
    __syncthreads();
    if (tid == 0) {
        double tsum = blkred[0] + blkred[1] + blkred[2] + blkred[3];
        if (bi != bj) tsum *= 2.0;                     // transpose block identical
        int qi = (brow < NB) ? ((bcol < NB) ? 0 : 2) : 1;
        atomicAdd(&acc_out[qi * 32 + (t & 31)], tsum);
    }
}

// ---------------- kernel D: finalize ----------------
__global__ void k_final(const double* __restrict__ wsd, float* __restrict__ out) {
    double xx = 0.0, yy = 0.0, xy2 = 0.0;
    for (int s = 0; s < 32; ++s) {
        xx  += wsd[WSD_ACC + s];
        yy  += wsd[WSD_ACC + 32 + s];
        xy2 += wsd[WSD_ACC + 64 + s];
    }
    double inv = 1.0 / ((double)NB * (double)NB);
    out[0] = (float)(wsd[0] * (xx * inv) + yy * inv - xy2 * inv);
}

extern "C" void kernel_launch(void* const* d_in, const int* in_sizes, int n_in,
                              void* d_out, int out_size, void* d_ws, size_t ws_size,
                              hipStream_t stream) {
    const float* src = (const float*)d_in[0];
    const float* tgt = (const float*)d_in[1];
    const float* s1  = (const float*)d_in[2];
    const float* s2  = (const float*)d_in[3];
    float* out = (float*)d_out;

    char* ws = (char*)d_ws;
    double* wsd = (double*)ws;
    float* scale_p = (float*)(ws + 8);
    double* m = wsd + WSD_M;
    float* sq = (float*)(ws + WS_SQ_OFF);
    unsigned short* tot = (unsigned short*)(ws + WS_TOT_OFF);

    const int ntri = NBLK * (NBLK + 1) / 2;   // 2080 upper-triangular blocks

    hipLaunchKernelGGL(k_zero,   dim3(1),      dim3(256), 0, stream, wsd);
    hipLaunchKernelGGL(k_rows,   dim3(NTOT/4), dim3(256), 0, stream, src, tgt, sq, tot);
    hipLaunchKernelGGL(k_colsum, dim3(256),    dim3(256), 0, stream, src, tgt, m);
    hipLaunchKernelGGL(k_consts, dim3(1),      dim3(256), 0, stream, s1, s2, sq, wsd, scale_p);
    hipLaunchKernelGGL(k_mmd,    dim3(ntri),   dim3(256), 0, stream, tot, sq, scale_p, wsd + WSD_ACC);
    hipLaunchKernelGGL(k_final,  dim3(1),      dim3(1),   0, stream, wsd, out);
}

// Round 4
// 74.209 us; speedup vs baseline: 2.7731x; 1.0783x over previous
//
#include <hip/hip_runtime.h>
#include <hip/hip_bf16.h>
#include <stdint.h>

// Problem constants
#define NB   4096      // rows per input matrix
#define DTOT 256       // feature dim
#define NTOT 8192      // 2*NB
#define NBLK 64        // 8192 / 128 tile blocks per side

// Workspace layout (bytes):
//   wsd[0]              wfac = Sw^2/(Sw^2+1e-8)
//   ws+8                float scale = log2(e)/bandwidth
//   wsd[2..98)          acc slots: [q*32 + s], q=0:XX 1:YY 2:XY+YX
//   ws+1024             float colpart[64][256]   (64 KB)
//   ws+66560            float sq[8192]           (32 KB)
//   ws+99328            ushort tot[8192*256] bf16 (4 MB)
#define WSD_ACC     2
#define WS_COL_OFF  1024
#define WS_SQ_OFF   66560
#define WS_TOT_OFF  99328

typedef __attribute__((ext_vector_type(8))) short bf16x8;
typedef __attribute__((ext_vector_type(4))) float f32x4;

__device__ __forceinline__ unsigned short f2bf(float f) {
    unsigned int u = __float_as_uint(f);
    unsigned int r = (u + 0x7FFFu + ((u >> 16) & 1u)) >> 16;   // RNE
    return (unsigned short)r;
}

// ---------------- kernel A: row sq-norms + bf16 convert ----------------
__global__ __launch_bounds__(256) void k_rows(const float* __restrict__ src,
                                              const float* __restrict__ tgt,
                                              float* __restrict__ sq,
                                              unsigned short* __restrict__ tot) {
    int lane = threadIdx.x & 63;
    int rsub = threadIdx.x >> 6;
    int r = blockIdx.x * 4 + rsub;
    const float* p = (r < NB) ? (src + (size_t)r * DTOT)
                              : (tgt + (size_t)(r - NB) * DTOT);
    float4 v = *(const float4*)(p + lane * 4);
    float s = v.x * v.x + v.y * v.y + v.z * v.z + v.w * v.w;
    ushort4 u;
    u.x = f2bf(v.x); u.y = f2bf(v.y); u.z = f2bf(v.z); u.w = f2bf(v.w);
    *(ushort4*)(tot + (size_t)r * DTOT + lane * 4) = u;
    for (int off = 32; off; off >>= 1) s += __shfl_down(s, off, 64);
    if (lane == 0) sq[r] = s;
}

// ---------------- kernel A2: column partial sums (atomic-free) ----------------
__global__ __launch_bounds__(256) void k_colsum(const float* __restrict__ src,
                                                const float* __restrict__ tgt,
                                                float* __restrict__ colpart) {
    int c = threadIdx.x;
    int r0 = blockIdx.x * 128;
    float s = 0.0f;
    for (int k = 0; k < 128; ++k) {
        int r = r0 + k;
        const float* p = (r < NB) ? (src + (size_t)r * DTOT)
                                  : (tgt + (size_t)(r - NB) * DTOT);
        s += p[c];
    }
    colpart[blockIdx.x * 256 + c] = s;
}

// ---------------- kernel B: bandwidth + weighting consts; zeroes acc ----------------
__global__ __launch_bounds__(256) void k_consts(const float* __restrict__ s1,
                                                const float* __restrict__ s2,
                                                const float* __restrict__ sq,
                                                const float* __restrict__ colpart,
                                                double* __restrict__ wsd,
                                                float* __restrict__ scale_out) {
    __shared__ double red[256];
    int t = threadIdx.x;
    // Sw = sum sigmoid(|s1-s2|)  (float math; wfac = 1 - O(1e-15) regardless)
    float swf = 0.0f;
    for (int i = t; i < NB; i += 256) {
        float d = fabsf(s1[i] - s2[i]);
        swf += 1.0f / (1.0f + exp2f(-d * 1.442695041f));
    }
    red[t] = (double)swf; __syncthreads();
    for (int off = 128; off; off >>= 1) { if (t < off) red[t] += red[t + off]; __syncthreads(); }
    double Sw = red[0]; __syncthreads();
    // S = sum of row sq-norms
    float ssf = 0.0f;
    for (int i = t; i < NTOT; i += 256) ssf += sq[i];
    red[t] = (double)ssf; __syncthreads();
    for (int off = 128; off; off >>= 1) { if (t < off) red[t] += red[t + off]; __syncthreads(); }
    double S = red[0]; __syncthreads();
    // ||sum x||^2 : thread t owns column t
    float mc = 0.0f;
    for (int b = 0; b < 64; ++b) mc += colpart[b * 256 + t];
    red[t] = (double)mc * (double)mc; __syncthreads();
    for (int off = 128; off; off >>= 1) { if (t < off) red[t] += red[t + off]; __syncthreads(); }
    if (t == 0) {
        double M2 = red[0];
        double sumL2 = 2.0 * (double)NTOT * S - 2.0 * M2;   // clamp effect negligible (diag ~ 0)
        double nn = (double)NTOT * (double)NTOT - (double)NTOT;
        double bw = (sumL2 / nn) * 0.25;                    // / KERNEL_MUL^(KERNEL_NUM//2)
        double SW = Sw * Sw;
        wsd[0] = SW / (SW + 1e-8);                          // wfac
        *scale_out = (float)(1.4426950408889634 / bw);      // log2(e)/bw
    }
    // zero accumulator slots (runs before k_mmd on the in-order stream)
    if (t < 96) wsd[WSD_ACC + t] = 0.0;
}

// ---------------- kernel C: fused GEMM + RBF epilogue, upper-triangular, swizzled LDS ----------------
// LDS tile [128 rows][8 chunks of 16B]; chunk c of row r holds global chunk c ^ (r&7).
// global_load_lds writes linearly (lane*16B); the SOURCE address carries the swizzle.
__global__ __launch_bounds__(256) void k_mmd(const unsigned short* __restrict__ tot,
                                             const float* __restrict__ sq,
                                             const float* __restrict__ scale_p,
                                             double* __restrict__ acc_out) {
    __shared__ unsigned short lds_a[128 * 64];
    __shared__ unsigned short lds_b[128 * 64];
    __shared__ double blkred[4];

    // decode upper-triangular block index: t -> (bi, bj), bi <= bj
    const int t = blockIdx.x;
    int bi = (int)((2.0f * NBLK + 1.0f
                    - sqrtf((2.0f * NBLK + 1.0f) * (2.0f * NBLK + 1.0f) - 8.0f * (float)t)) * 0.5f);
    while (bi > 0 && bi * (2 * NBLK - bi + 1) / 2 > t) --bi;
    while ((bi + 1) * (2 * NBLK - bi) / 2 <= t) ++bi;
    const int bj = bi + (t - bi * (2 * NBLK - bi + 1) / 2);

    const int tid  = threadIdx.x;
    const int lane = tid & 63;
    const int wid  = tid >> 6;
    const int brow = bi * 128;
    const int bcol = bj * 128;
    const int wm = wid >> 1, wn = wid & 1;

    const unsigned short* gA = tot + (size_t)brow * DTOT;
    const unsigned short* gB = tot + (size_t)bcol * DTOT;

    f32x4 acc[4][4] = {};

    const int rLan = lane >> 3;                       // row-within-8 for staging
    const int cSwz = ((lane & 7) ^ rLan) * 8;         // swizzled source element offset

    for (int ki = 0; ki < 4; ++ki) {
        const int cOff = ki * 64 + cSwz;
#pragma unroll
        for (int q = 0; q < 4; ++q) {
            const int row0 = wid * 32 + q * 8;
            const unsigned short* ga = gA + (size_t)(row0 + rLan) * DTOT + cOff;
            __builtin_amdgcn_global_load_lds(
                (const __attribute__((address_space(1))) void*)ga,
                (__attribute__((address_space(3))) void*)(lds_a + row0 * 64),
                16, 0, 0);
        }
#pragma unroll
        for (int q = 0; q < 4; ++q) {
            const int row0 = wid * 32 + q * 8;
            const unsigned short* gb = gB + (size_t)(row0 + rLan) * DTOT + cOff;
            __builtin_amdgcn_global_load_lds(
                (const __attribute__((address_space(1))) void*)gb,
                (__attribute__((address_space(3))) void*)(lds_b + row0 * 64),
                16, 0, 0);
        }
        __syncthreads();
#pragma unroll
        for (int kk = 0; kk < 2; ++kk) {
            // desired global chunk g = kk*4 + (lane>>4); stored at chunk g ^ (row&7), row&7 == lane&7
            const int cxor = ((kk * 4 + (lane >> 4)) ^ (lane & 7)) * 8;
            bf16x8 af[4], bfr[4];
#pragma unroll
            for (int mi = 0; mi < 4; ++mi)
                af[mi] = *(const bf16x8*)(lds_a + (wm * 64 + mi * 16 + (lane & 15)) * 64 + cxor);
#pragma unroll
            for (int ni = 0; ni < 4; ++ni)
                bfr[ni] = *(const bf16x8*)(lds_b + (wn * 64 + ni * 16 + (lane & 15)) * 64 + cxor);
#pragma unroll
            for (int mi = 0; mi < 4; ++mi)
#pragma unroll
                for (int ni = 0; ni < 4; ++ni)
                    acc[mi][ni] = __builtin_amdgcn_mfma_f32_16x16x32_bf16(
                        af[mi], bfr[ni], acc[mi][ni], 0, 0, 0);
        }
        __syncthreads();
    }

    // ---- fused epilogue: L2 -> 5-bandwidth RBF sum -> quadrant accumulate ----
    const float scale = *scale_p;   // log2(e)/bw
    float part = 0.0f;
    float sqj[4];
#pragma unroll
    for (int ni = 0; ni < 4; ++ni)
        sqj[ni] = sq[bcol + wn * 64 + ni * 16 + (lane & 15)];
#pragma unroll
    for (int mi = 0; mi < 4; ++mi) {
        float sqi[4];
#pragma unroll
        for (int r = 0; r < 4; ++r)
            sqi[r] = sq[brow + wm * 64 + mi * 16 + (lane >> 4) * 4 + r];
#pragma unroll
        for (int ni = 0; ni < 4; ++ni) {
#pragma unroll
            for (int r = 0; r < 4; ++r) {
                float l2 = sqi[r] + sqj[ni] - 2.0f * acc[mi][ni][r];
                l2 = fmaxf(l2, 0.0f);
                float a = l2 * scale;
                float k4 = exp2f(-a * 0.0625f);   // exp(-L2/(bw*16))
                float k3 = k4 * k4;
                float k2 = k3 * k3;
                float k1 = k2 * k2;
                float k0 = k1 * k1;
                part += ((k4 + k3) + (k2 + k1)) + k0;
            }
        }
    }
    for (int off = 32; off; off >>= 1) part += __shfl_down(part, off, 64);
    if (lane == 0) blkred[wid] = (double)part;
    __syncthreads();
    if (tid == 0) {
        double tsum = blkred[0] + blkred[1] + blkred[2] + blkred[3];
        if (bi != bj) tsum *= 2.0;                     // transpose block identical
        int qi = (brow < NB) ? ((bcol < NB) ? 0 : 2) : 1;
        atomicAdd(&acc_out[qi * 32 + (t & 31)], tsum);
    }
}

// ---------------- kernel D: finalize ----------------
__global__ __launch_bounds__(128) void k_final(const double* __restrict__ wsd,
                                               float* __restrict__ out) {
    __shared__ double sred[128];
    int t = threadIdx.x;
    double wfac = wsd[0];
    double v = 0.0;
    if (t < 96) {
        v = wsd[WSD_ACC + t];
        if (t < 32)      v *= wfac;     // XX weighted
        else if (t >= 64) v = -v;       // -(XY+YX)
    }
    sred[t] = v; __syncthreads();
    for (int off = 64; off; off >>= 1) { if (t < off) sred[t] += sred[t + off]; __syncthreads(); }
    if (t == 0) {
        double inv = 1.0 / ((double)NB * (double)NB);
        out[0] = (float)(sred[0] * inv);
    }
}

extern "C" void kernel_launch(void* const* d_in, const int* in_sizes, int n_in,
                              void* d_out, int out_size, void* d_ws, size_t ws_size,
                              hipStream_t stream) {
    const float* src = (const float*)d_in[0];
    const float* tgt = (const float*)d_in[1];
    const float* s1  = (const float*)d_in[2];
    const float* s2  = (const float*)d_in[3];
    float* out = (float*)d_out;

    char* ws = (char*)d_ws;
    double* wsd = (double*)ws;
    float* scale_p = (float*)(ws + 8);
    float* colpart = (float*)(ws + WS_COL_OFF);
    float* sq = (float*)(ws + WS_SQ_OFF);
    unsigned short* tot = (unsigned short*)(ws + WS_TOT_OFF);

    const int ntri = NBLK * (NBLK + 1) / 2;   // 2080 upper-triangular blocks

    hipLaunchKernelGGL(k_rows,   dim3(NTOT/4), dim3(256), 0, stream, src, tgt, sq, tot);
    hipLaunchKernelGGL(k_colsum, dim3(64),     dim3(256), 0, stream, src, tgt, colpart);
    hipLaunchKernelGGL(k_consts, dim3(1),      dim3(256), 0, stream, s1, s2, sq, colpart, wsd, scale_p);
    hipLaunchKernelGGL(k_mmd,    dim3(ntri),   dim3(256), 0, stream, tot, sq, scale_p, wsd + WSD_ACC);
    hipLaunchKernelGGL(k_final,  dim3(1),      dim3(128), 0, stream, wsd, out);
}